// Round 6
// baseline (110.463 us; speedup 1.0000x reference)
//
#include <hip/hip_runtime.h>

#define B 4
#define T 256
#define S 512
#define H 512
#define H4 (H/4)          // 128
#define BTS (B*T*S)       // 524288
#define PS (3072*512)     // split-K partial stride
#define NKZ 8             // split-K factor

// 2 * log2(e): projections are prescaled so exp2 replaces exp.
#define PRESCALE 2.8853900817779268f
#define LOG2E 1.4426950408889634f

#if __has_builtin(__builtin_amdgcn_exp2f)
#define EXP2(x) __builtin_amdgcn_exp2f(x)
#else
#define EXP2(x) exp2f(x)
#endif

// ---------------------------------------------------------------------------
// K1a: split-K projection GEMM.  part[kz][m][n] = sum_{k in chunk} A[m,k]*W[n,k]
// Tile 128m x 128n, micro 8x8 per thread as 2x2 blocks of 4x4
// (reads at tn*4 and 64+tn*4: 2-way LDS bank aliasing = free).
// 1 B LDS-read per FLOP. Grid (4 n, 24 m, 8 kz) = 768 blocks -> 3/CU.
// ---------------------------------------------------------------------------
__global__ __launch_bounds__(256) void proj_split(
    const float* __restrict__ dh, const float* __restrict__ enc,
    const float* __restrict__ W1, const float* __restrict__ W2,
    float* __restrict__ part)
{
    __shared__ float As[16][128];
    __shared__ float Ws[16][128];

    const int tid   = threadIdx.x;
    const int n0    = blockIdx.x * 128;
    const int mTile = blockIdx.y;          // 0..23
    const int kz    = blockIdx.z;          // 0..7

    const float* A; const float* W; int mbase;
    if (mTile < 8) { A = dh;  W = W1; mbase = mTile * 128; }
    else           { A = enc; W = W2; mbase = (mTile - 8) * 128; }

    const int lr = tid >> 1;            // staging row 0..127
    const int lh = (tid & 1) * 8;       // staging k-offset 0/8
    const int tm = (tid >> 4) * 4;      // micro row base (0,4,..,60)
    const int tn = (tid & 15) * 4;      // micro col base (0,4,..,60)

    float acc[2][4][2][4] = {};         // [mhalf][i][nhalf][j]

    const int k0 = kz * 64;
    for (int kc = k0; kc < k0 + 64; kc += 16) {
        float4 a0 = *(const float4*)&A[(size_t)(mbase + lr) * H + kc + lh];
        float4 a1 = *(const float4*)&A[(size_t)(mbase + lr) * H + kc + lh + 4];
        float4 w0 = *(const float4*)&W[(size_t)(n0 + lr) * H + kc + lh];
        float4 w1 = *(const float4*)&W[(size_t)(n0 + lr) * H + kc + lh + 4];
        __syncthreads();
        As[lh + 0][lr] = a0.x; As[lh + 1][lr] = a0.y;
        As[lh + 2][lr] = a0.z; As[lh + 3][lr] = a0.w;
        As[lh + 4][lr] = a1.x; As[lh + 5][lr] = a1.y;
        As[lh + 6][lr] = a1.z; As[lh + 7][lr] = a1.w;
        Ws[lh + 0][lr] = w0.x; Ws[lh + 1][lr] = w0.y;
        Ws[lh + 2][lr] = w0.z; Ws[lh + 3][lr] = w0.w;
        Ws[lh + 4][lr] = w1.x; Ws[lh + 5][lr] = w1.y;
        Ws[lh + 6][lr] = w1.z; Ws[lh + 7][lr] = w1.w;
        __syncthreads();
        #pragma unroll
        for (int kk = 0; kk < 16; ++kk) {
            float4 am0 = *(const float4*)&As[kk][tm];
            float4 am1 = *(const float4*)&As[kk][64 + tm];
            float4 wn0 = *(const float4*)&Ws[kk][tn];
            float4 wn1 = *(const float4*)&Ws[kk][64 + tn];
            float a8[2][4] = {{am0.x, am0.y, am0.z, am0.w},
                              {am1.x, am1.y, am1.z, am1.w}};
            float w8[2][4] = {{wn0.x, wn0.y, wn0.z, wn0.w},
                              {wn1.x, wn1.y, wn1.z, wn1.w}};
            #pragma unroll
            for (int mh = 0; mh < 2; ++mh)
                #pragma unroll
                for (int i = 0; i < 4; ++i)
                    #pragma unroll
                    for (int nh = 0; nh < 2; ++nh)
                        #pragma unroll
                        for (int j = 0; j < 4; ++j)
                            acc[mh][i][nh][j] += a8[mh][i] * w8[nh][j];
        }
    }

    float* outp = part + (size_t)kz * PS;
    #pragma unroll
    for (int mh = 0; mh < 2; ++mh)
        #pragma unroll
        for (int i = 0; i < 4; ++i) {
            const int grow = mTile * 128 + mh * 64 + tm + i;
            #pragma unroll
            for (int nh = 0; nh < 2; ++nh)
                *(float4*)&outp[(size_t)grow * 512 + n0 + nh * 64 + tn] =
                    make_float4(acc[mh][i][nh][0], acc[mh][i][nh][1],
                                acc[mh][i][nh][2], acc[mh][i][nh][3]);
        }
}

// ---------------------------------------------------------------------------
// K1b: epilogue. sum NKZ partials + bias -> exp2(min(x*PRESCALE,126)).
// Blocks 0..127:   q rows (0..1023) -> abuf row-major.
// Blocks 128..383: k rows in 64x64 tiles -> bT4[b][h/4][s][4] via LDS transpose.
// ---------------------------------------------------------------------------
__global__ __launch_bounds__(256) void exp_trans(
    const float* __restrict__ part,
    const float* __restrict__ b1, const float* __restrict__ b2,
    float* __restrict__ abuf, float* __restrict__ bT4)
{
    const int tid = threadIdx.x;

    if (blockIdx.x < 128) {
        #pragma unroll
        for (int j = 0; j < 4; ++j) {
            const int f = blockIdx.x * 256 + tid + j * 32768;
            float4 bv = *(const float4*)&b1[(f & 127) * 4];
            float sx = bv.x, sy = bv.y, sz = bv.z, sw = bv.w;
            #pragma unroll
            for (int c = 0; c < NKZ; ++c) {
                float4 v = ((const float4*)(part + (size_t)c * PS))[f];
                sx += v.x; sy += v.y; sz += v.z; sw += v.w;
            }
            float4 o;
            o.x = EXP2(fminf(sx * PRESCALE, 126.f));
            o.y = EXP2(fminf(sy * PRESCALE, 126.f));
            o.z = EXP2(fminf(sz * PRESCALE, 126.f));
            o.w = EXP2(fminf(sw * PRESCALE, 126.f));
            ((float4*)abuf)[f] = o;
        }
    } else {
        __shared__ float TT[64][65];
        const int kb   = blockIdx.x - 128;
        const int rt   = kb >> 3;          // 0..31 (row tile of 64 k-rows)
        const int ct   = kb & 7;           // 0..7  (col tile of 64 h)
        const int r16  = tid >> 4;         // 0..15
        const int col4 = tid & 15;         // float4 col within tile

        #pragma unroll
        for (int jj = 0; jj < 4; ++jj) {
            const int r = r16 + jj * 16;                 // 0..63
            const size_t grow = 1024 + (size_t)rt * 64 + r;
            const size_t off  = grow * 512 + ct * 64 + col4 * 4;
            float4 bv = *(const float4*)&b2[ct * 64 + col4 * 4];
            float sx = bv.x, sy = bv.y, sz = bv.z, sw = bv.w;
            #pragma unroll
            for (int c = 0; c < NKZ; ++c) {
                float4 v = *(const float4*)&part[off + (size_t)c * PS];
                sx += v.x; sy += v.y; sz += v.z; sw += v.w;
            }
            TT[r][col4 * 4 + 0] = EXP2(fminf(sx * PRESCALE, 126.f));
            TT[r][col4 * 4 + 1] = EXP2(fminf(sy * PRESCALE, 126.f));
            TT[r][col4 * 4 + 2] = EXP2(fminf(sz * PRESCALE, 126.f));
            TT[r][col4 * 4 + 3] = EXP2(fminf(sw * PRESCALE, 126.f));
        }
        __syncthreads();

        const int sl = tid & 63;           // s within tile
        const int hq = tid >> 6;           // 0..3
        const int gs = rt * 64 + sl;       // k row 0..2047
        const int bb = gs >> 9;
        const int ss = gs & 511;
        #pragma unroll
        for (int jj = 0; jj < 4; ++jj) {
            const int hl = hq * 16 + jj * 4;
            float4 v = make_float4(TT[sl][hl + 0], TT[sl][hl + 1],
                                   TT[sl][hl + 2], TT[sl][hl + 3]);
            const int h = ct * 64 + hl;
            *(float4*)&bT4[((size_t)(bb * H4 + (h >> 2)) * S + ss) * 4] = v;
        }
    }
}

// ---------------------------------------------------------------------------
// K2: score partials.  full score = sum_h V[h] - 2*sum_h V[h]*rcp(a*b+1) + bV
// ---------------------------------------------------------------------------
__global__ __launch_bounds__(256) void score_kernel(
    const float* __restrict__ abuf, const float* __restrict__ bT4,
    const float* __restrict__ Vp, const float* __restrict__ bVp,
    float* __restrict__ spart)
{
    const int tid  = threadIdx.x;
    const int lane = tid & 63;
    const int w    = tid >> 6;
    const int b    = blockIdx.z >> 2;
    const int c    = blockIdx.z & 3;           // h-chunk
    const int t0   = blockIdx.y * 16 + w * 4;
    const int s0   = blockIdx.x * 64;
    const int h0   = c * 128;

    float pv = Vp[h0 + lane] + Vp[h0 + 64 + lane];
    #pragma unroll
    for (int off = 32; off; off >>= 1) pv += __shfl_xor(pv, off);
    if (c == 0) pv += bVp[0];

    const float* a0 = abuf + __builtin_amdgcn_readfirstlane((b * T + t0 + 0) * H);
    const float* a1 = abuf + __builtin_amdgcn_readfirstlane((b * T + t0 + 1) * H);
    const float* a2 = abuf + __builtin_amdgcn_readfirstlane((b * T + t0 + 2) * H);
    const float* a3 = abuf + __builtin_amdgcn_readfirstlane((b * T + t0 + 3) * H);

    const float4* bp = (const float4*)bT4 + (size_t)(b * H4 + (h0 >> 2)) * S + s0 + lane;

    float acc0 = 0.f, acc1 = 0.f, acc2 = 0.f, acc3 = 0.f;

    #pragma unroll 4
    for (int h4 = 0; h4 < 32; ++h4) {
        const int h = h0 + h4 * 4;
        float4 kb = bp[(size_t)h4 * S];
        float4 v4  = *(const float4*)&Vp[h];
        float4 qa0 = *(const float4*)&a0[h];
        float4 qa1 = *(const float4*)&a1[h];
        float4 qa2 = *(const float4*)&a2[h];
        float4 qa3 = *(const float4*)&a3[h];

        acc0 = fmaf(v4.x, __builtin_amdgcn_rcpf(fmaf(qa0.x, kb.x, 1.f)), acc0);
        acc0 = fmaf(v4.y, __builtin_amdgcn_rcpf(fmaf(qa0.y, kb.y, 1.f)), acc0);
        acc0 = fmaf(v4.z, __builtin_amdgcn_rcpf(fmaf(qa0.z, kb.z, 1.f)), acc0);
        acc0 = fmaf(v4.w, __builtin_amdgcn_rcpf(fmaf(qa0.w, kb.w, 1.f)), acc0);

        acc1 = fmaf(v4.x, __builtin_amdgcn_rcpf(fmaf(qa1.x, kb.x, 1.f)), acc1);
        acc1 = fmaf(v4.y, __builtin_amdgcn_rcpf(fmaf(qa1.y, kb.y, 1.f)), acc1);
        acc1 = fmaf(v4.z, __builtin_amdgcn_rcpf(fmaf(qa1.z, kb.z, 1.f)), acc1);
        acc1 = fmaf(v4.w, __builtin_amdgcn_rcpf(fmaf(qa1.w, kb.w, 1.f)), acc1);

        acc2 = fmaf(v4.x, __builtin_amdgcn_rcpf(fmaf(qa2.x, kb.x, 1.f)), acc2);
        acc2 = fmaf(v4.y, __builtin_amdgcn_rcpf(fmaf(qa2.y, kb.y, 1.f)), acc2);
        acc2 = fmaf(v4.z, __builtin_amdgcn_rcpf(fmaf(qa2.z, kb.z, 1.f)), acc2);
        acc2 = fmaf(v4.w, __builtin_amdgcn_rcpf(fmaf(qa2.w, kb.w, 1.f)), acc2);

        acc3 = fmaf(v4.x, __builtin_amdgcn_rcpf(fmaf(qa3.x, kb.x, 1.f)), acc3);
        acc3 = fmaf(v4.y, __builtin_amdgcn_rcpf(fmaf(qa3.y, kb.y, 1.f)), acc3);
        acc3 = fmaf(v4.z, __builtin_amdgcn_rcpf(fmaf(qa3.z, kb.z, 1.f)), acc3);
        acc3 = fmaf(v4.w, __builtin_amdgcn_rcpf(fmaf(qa3.w, kb.w, 1.f)), acc3);
    }

    float* out = spart + (size_t)c * BTS;
    const int base = (b * T + t0) * S + s0 + lane;
    out[base + 0 * S] = fmaf(-2.f, acc0, pv);
    out[base + 1 * S] = fmaf(-2.f, acc1, pv);
    out[base + 2 * S] = fmaf(-2.f, acc2, pv);
    out[base + 3 * S] = fmaf(-2.f, acc3, pv);
}

// ---------------------------------------------------------------------------
// K3a: softmax. 8 rows per block (2 per wave). Sums 4 spart chunks.
// ---------------------------------------------------------------------------
__global__ __launch_bounds__(256) void softmax_k(
    const float* __restrict__ spart, float* __restrict__ attnb)
{
    const int lane = threadIdx.x & 63;
    const int w    = threadIdx.x >> 6;

    #pragma unroll
    for (int r = 0; r < 2; ++r) {
        const int row = blockIdx.x * 8 + w * 2 + r;
        const size_t base = (size_t)row * S + lane * 4;

        float4 x0 = make_float4(0.f, 0.f, 0.f, 0.f);
        float4 x1 = make_float4(0.f, 0.f, 0.f, 0.f);
        #pragma unroll
        for (int c = 0; c < 4; ++c) {
            float4 u = *(const float4*)&spart[base + (size_t)c * BTS];
            float4 v = *(const float4*)&spart[base + (size_t)c * BTS + 256];
            x0.x += u.x; x0.y += u.y; x0.z += u.z; x0.w += u.w;
            x1.x += v.x; x1.y += v.y; x1.z += v.z; x1.w += v.w;
        }

        float m = fmaxf(fmaxf(fmaxf(x0.x, x0.y), fmaxf(x0.z, x0.w)),
                        fmaxf(fmaxf(x1.x, x1.y), fmaxf(x1.z, x1.w)));
        #pragma unroll
        for (int off = 32; off; off >>= 1) m = fmaxf(m, __shfl_xor(m, off));

        float4 e0, e1;
        e0.x = EXP2((x0.x - m) * LOG2E); e0.y = EXP2((x0.y - m) * LOG2E);
        e0.z = EXP2((x0.z - m) * LOG2E); e0.w = EXP2((x0.w - m) * LOG2E);
        e1.x = EXP2((x1.x - m) * LOG2E); e1.y = EXP2((x1.y - m) * LOG2E);
        e1.z = EXP2((x1.z - m) * LOG2E); e1.w = EXP2((x1.w - m) * LOG2E);

        float sum = e0.x + e0.y + e0.z + e0.w + e1.x + e1.y + e1.z + e1.w;
        #pragma unroll
        for (int off = 32; off; off >>= 1) sum += __shfl_xor(sum, off);
        const float inv = __builtin_amdgcn_rcpf(sum);

        e0.x *= inv; e0.y *= inv; e0.z *= inv; e0.w *= inv;
        e1.x *= inv; e1.y *= inv; e1.z *= inv; e1.w *= inv;
        *(float4*)&attnb[base]       = e0;
        *(float4*)&attnb[base + 256] = e1;
    }
}

// ---------------------------------------------------------------------------
// K3b: context = attn @ enc.  Block = (b, 16 t, 64 h); attn tile in LDS.
// Grid (8 hc, 16 tt, 4 b) = 512 blocks.
// ---------------------------------------------------------------------------
__global__ __launch_bounds__(256) void ctx_kernel(
    const float* __restrict__ attnb, const float* __restrict__ enc,
    float* __restrict__ out)
{
    __shared__ float at[16][512];

    const int tid = threadIdx.x;
    const int h0  = blockIdx.x * 64;
    const int t0  = blockIdx.y * 16;
    const int b   = blockIdx.z;

    // stage attn tile: 16 rows x 512 = 2048 float4, 8 per thread
    #pragma unroll
    for (int j = 0; j < 8; ++j) {
        const int fidx = j * 256 + tid;        // float4 index
        const int row  = fidx >> 7;            // 128 float4 per row
        const int col  = (fidx & 127) * 4;
        float4 v = *(const float4*)&attnb[(size_t)(b * T + t0 + row) * S + col];
        *(float4*)&at[row][col] = v;
    }
    __syncthreads();

    const int tt = tid >> 4;         // 0..15 (t within tile)
    const int tc = (tid & 15) * 4;   // h offset within chunk

    float4 acc = make_float4(0.f, 0.f, 0.f, 0.f);
    #pragma unroll 8
    for (int s = 0; s < S; ++s) {
        const float a = at[tt][s];
        float4 e4 = *(const float4*)&enc[(size_t)(b * S + s) * H + h0 + tc];
        acc.x = fmaf(a, e4.x, acc.x);
        acc.y = fmaf(a, e4.y, acc.y);
        acc.z = fmaf(a, e4.z, acc.z);
        acc.w = fmaf(a, e4.w, acc.w);
    }

    *(float4*)&out[(size_t)(b * T + t0 + tt) * H + h0 + tc] = acc;
}

extern "C" void kernel_launch(void* const* d_in, const int* in_sizes, int n_in,
                              void* d_out, int out_size, void* d_ws, size_t ws_size,
                              hipStream_t stream) {
    const float* dh  = (const float*)d_in[0];
    const float* enc = (const float*)d_in[1];
    const float* W1  = (const float*)d_in[2];
    const float* b1  = (const float*)d_in[3];
    const float* W2  = (const float*)d_in[4];
    const float* b2  = (const float*)d_in[5];
    const float* V   = (const float*)d_in[6];
    const float* bV  = (const float*)d_in[7];

    float* ws    = (float*)d_ws;
    float* part  = ws;                          // NKZ*PS floats (50.3 MB)
    float* spart = ws;                          // aliases part (dead by K2)
    float* abuf  = ws + (size_t)NKZ * PS;       // B*T*H = 524288
    float* bT4   = abuf + (size_t)B * T * H;    // B*S*H = 1048576
    float* attnb = bT4 + (size_t)B * S * H;     // B*T*S = 524288

    dim3 blk(256);
    proj_split  <<<dim3(4, 24, 8),  blk, 0, stream>>>(dh, enc, W1, W2, part);
    exp_trans   <<<dim3(384),       blk, 0, stream>>>(part, b1, b2, abuf, bT4);
    score_kernel<<<dim3(8, 16, 16), blk, 0, stream>>>(abuf, bT4, V, bV, spart);
    softmax_k   <<<dim3(128),       blk, 0, stream>>>(spart, attnb);
    ctx_kernel  <<<dim3(8, 16, 4),  blk, 0, stream>>>(attnb, enc, (float*)d_out);
}

// Round 7
// 86.416 us; speedup vs baseline: 1.2783x; 1.2783x over previous
//
#include <hip/hip_runtime.h>

#define B 4
#define T 256
#define S 512
#define H 512
#define BTS (B*T*S)       // 524288

// 2 * log2(e): projections are prescaled so exp2 replaces exp in tanh.
#define PRESCALE 2.8853900817779268f
#define LOG2E 1.4426950408889634f
#define QCLAMP 15.0f      // clamp exp2 arg: ab <= 2^30, den (4-way) <= 2^120

typedef unsigned short u16;
typedef __attribute__((ext_vector_type(8))) short bf16x8;   // 8 bf16 in 4 VGPRs
typedef __attribute__((ext_vector_type(4))) float f32x4;

#if __has_builtin(__builtin_amdgcn_exp2f)
#define EXP2(x) __builtin_amdgcn_exp2f(x)
#else
#define EXP2(x) exp2f(x)
#endif

__device__ __forceinline__ u16 f2bf(float x) {              // RNE fp32->bf16
    unsigned u = __float_as_uint(x);
    u = u + 0x7FFFu + ((u >> 16) & 1u);
    return (u16)(u >> 16);
}
__device__ __forceinline__ float bf2f(u16 b) {
    return __uint_as_float(((unsigned)b) << 16);
}

// ---------------------------------------------------------------------------
// K0: split fp32 inputs into bf16 hi/lo pairs.
// A combined rows: 0..1023 = dh, 1024..3071 = enc.  W: 0..511 = W1, 512..1023 = W2.
// ---------------------------------------------------------------------------
__global__ __launch_bounds__(256) void convert_split(
    const float* __restrict__ dh, const float* __restrict__ enc,
    const float* __restrict__ W1, const float* __restrict__ W2,
    u16* __restrict__ Ahi, u16* __restrict__ Alo,
    u16* __restrict__ Whi, u16* __restrict__ Wlo)
{
    const int i4 = blockIdx.x * 256 + threadIdx.x;   // float4 index, 524288 total
    float4 v;
    if (i4 < 131072)      v = ((const float4*)dh)[i4];
    else if (i4 < 393216) v = ((const float4*)enc)[i4 - 131072];
    else if (i4 < 458752) v = ((const float4*)W1)[i4 - 393216];
    else                  v = ((const float4*)W2)[i4 - 458752];
    const u16 h0 = f2bf(v.x), h1 = f2bf(v.y), h2 = f2bf(v.z), h3 = f2bf(v.w);
    ushort4 hh = make_ushort4(h0, h1, h2, h3);
    ushort4 ll = make_ushort4(f2bf(v.x - bf2f(h0)), f2bf(v.y - bf2f(h1)),
                              f2bf(v.z - bf2f(h2)), f2bf(v.w - bf2f(h3)));
    if (i4 < 393216) { ((ushort4*)Ahi)[i4] = hh; ((ushort4*)Alo)[i4] = ll; }
    else             { ((ushort4*)Whi)[i4 - 393216] = hh; ((ushort4*)Wlo)[i4 - 393216] = ll; }
}

// ---------------------------------------------------------------------------
// K1: MFMA projection GEMM, split-bf16 (hi*hi + hi*lo + lo*hi), fused epilogue:
//   e = exp2(min((acc + bias)*PRESCALE, QCLAMP))
//   q rows -> abuf[t][h] row-major; k rows -> bT4[b][h/4][s][4] (transposed).
// Block: 64m x 64n tile, 4 waves (each 32x32 as 2x2 of 16x16), BK=64.
// LDS tiles 16B-chunk XOR-swizzled (chunk ^= row&7) to kill 128B-stride conflicts.
// ---------------------------------------------------------------------------
__global__ __launch_bounds__(256) void mfma_proj(
    const u16* __restrict__ Ahi, const u16* __restrict__ Alo,
    const u16* __restrict__ Whi, const u16* __restrict__ Wlo,
    const float* __restrict__ b1, const float* __restrict__ b2,
    float* __restrict__ abuf, float* __restrict__ bT4)
{
    __shared__ u16 lds[4 * 4096];   // [mat: Ahi,Alo,Whi,Wlo][64 rows][64 k]

    const int tid   = threadIdx.x;
    const int lane  = tid & 63;
    const int w     = tid >> 6;
    const int n0    = blockIdx.x * 64;
    const int mTile = blockIdx.y;           // 0..47
    const int mbase = mTile * 64;
    const bool is_q = (mTile < 16);
    const int wrow  = (is_q ? 0 : 512) + n0;   // W tile row base

    const int wm = (w & 1) * 32;
    const int wn = (w >> 1) * 32;

    const int r0  = tid >> 3;               // staging row 0..31 (chunk 2: +32)
    const int kc0 = tid & 7;                // staging k-chunk

    f32x4 acc[2][2] = {};                   // [ms][ns]

    for (int kb = 0; kb < 8; ++kb) {
        const int k0 = kb * 64;
        const size_t ga0 = (size_t)(mbase + r0) * 512 + k0 + kc0 * 8;
        const size_t ga1 = (size_t)(mbase + r0 + 32) * 512 + k0 + kc0 * 8;
        const size_t gw0 = (size_t)(wrow + r0) * 512 + k0 + kc0 * 8;
        const size_t gw1 = (size_t)(wrow + r0 + 32) * 512 + k0 + kc0 * 8;
        bf16x8 ah0 = *(const bf16x8*)&Ahi[ga0];
        bf16x8 ah1 = *(const bf16x8*)&Ahi[ga1];
        bf16x8 al0 = *(const bf16x8*)&Alo[ga0];
        bf16x8 al1 = *(const bf16x8*)&Alo[ga1];
        bf16x8 wh0 = *(const bf16x8*)&Whi[gw0];
        bf16x8 wh1 = *(const bf16x8*)&Whi[gw1];
        bf16x8 wl0 = *(const bf16x8*)&Wlo[gw0];
        bf16x8 wl1 = *(const bf16x8*)&Wlo[gw1];
        __syncthreads();
        const int sw  = (kc0 ^ (r0 & 7)) << 3;       // (r0+32)&7 == r0&7
        const int s0o = r0 * 64 + sw;
        const int s1o = (r0 + 32) * 64 + sw;
        *(bf16x8*)&lds[0 * 4096 + s0o] = ah0;  *(bf16x8*)&lds[0 * 4096 + s1o] = ah1;
        *(bf16x8*)&lds[1 * 4096 + s0o] = al0;  *(bf16x8*)&lds[1 * 4096 + s1o] = al1;
        *(bf16x8*)&lds[2 * 4096 + s0o] = wh0;  *(bf16x8*)&lds[2 * 4096 + s1o] = wh1;
        *(bf16x8*)&lds[3 * 4096 + s0o] = wl0;  *(bf16x8*)&lds[3 * 4096 + s1o] = wl1;
        __syncthreads();

        #pragma unroll
        for (int ks = 0; ks < 2; ++ks) {
            const int kg = ks * 4 + (lane >> 4);     // k-chunk 0..7
            bf16x8 amh[2], aml[2], bnh[2], bnl[2];
            #pragma unroll
            for (int ms = 0; ms < 2; ++ms) {
                const int row = wm + ms * 16 + (lane & 15);
                const int off = row * 64 + ((kg ^ (row & 7)) << 3);
                amh[ms] = *(const bf16x8*)&lds[0 * 4096 + off];
                aml[ms] = *(const bf16x8*)&lds[1 * 4096 + off];
            }
            #pragma unroll
            for (int ns = 0; ns < 2; ++ns) {
                const int row = wn + ns * 16 + (lane & 15);
                const int off = row * 64 + ((kg ^ (row & 7)) << 3);
                bnh[ns] = *(const bf16x8*)&lds[2 * 4096 + off];
                bnl[ns] = *(const bf16x8*)&lds[3 * 4096 + off];
            }
            #pragma unroll
            for (int ms = 0; ms < 2; ++ms)
                #pragma unroll
                for (int ns = 0; ns < 2; ++ns) {
                    acc[ms][ns] = __builtin_amdgcn_mfma_f32_16x16x32_bf16(amh[ms], bnh[ns], acc[ms][ns], 0, 0, 0);
                    acc[ms][ns] = __builtin_amdgcn_mfma_f32_16x16x32_bf16(amh[ms], bnl[ns], acc[ms][ns], 0, 0, 0);
                    acc[ms][ns] = __builtin_amdgcn_mfma_f32_16x16x32_bf16(aml[ms], bnh[ns], acc[ms][ns], 0, 0, 0);
                }
        }
    }

    // fused epilogue: bias + prescale + exp2, dual-layout store
    const float* bias = is_q ? b1 : b2;
    #pragma unroll
    for (int ns = 0; ns < 2; ++ns) {
        const int gn = n0 + wn + ns * 16 + (lane & 15);
        const float bv = bias[gn];
        #pragma unroll
        for (int ms = 0; ms < 2; ++ms) {
            #pragma unroll
            for (int r = 0; r < 4; ++r) {
                const int gm = mbase + wm + ms * 16 + (lane >> 4) * 4 + r;
                const float e = EXP2(fminf((acc[ms][ns][r] + bv) * PRESCALE, QCLAMP));
                if (is_q) {
                    abuf[(size_t)gm * 512 + gn] = e;
                } else {
                    const int srow = gm - 1024;
                    const int bb = srow >> 9, ss = srow & 511;
                    bT4[(((size_t)(bb * 128 + (gn >> 2)) * 512) + ss) * 4 + (gn & 3)] = e;
                }
            }
        }
    }
}

// ---------------------------------------------------------------------------
// K2: score partials.  score = sum_h V[h] - 2*sum_h V[h]/(a*b+1) + bV
// 4-way rcp batching: sum V_i/x_i = [(V0x1+V1x0)p23 + (V2x3+V3x2)p01] / (p01*p23)
//   -> 14 VALU + 1 trans per 4 elements (was 2 VALU + 1 trans per element).
// ---------------------------------------------------------------------------
__device__ __forceinline__ float quad_term(float4 qa, float4 kb, float4 v4, float acc) {
    float x0 = fmaf(qa.x, kb.x, 1.f);
    float x1 = fmaf(qa.y, kb.y, 1.f);
    float x2 = fmaf(qa.z, kb.z, 1.f);
    float x3 = fmaf(qa.w, kb.w, 1.f);
    float p01 = x0 * x1, p23 = x2 * x3;
    float n01 = fmaf(v4.y, x0, v4.x * x1);
    float n23 = fmaf(v4.w, x2, v4.z * x3);
    float num = fmaf(n23, p01, n01 * p23);
    float den = p01 * p23;
    return fmaf(num, __builtin_amdgcn_rcpf(den), acc);
}

__global__ __launch_bounds__(256) void score_kernel(
    const float* __restrict__ abuf, const float* __restrict__ bT4,
    const float* __restrict__ Vp, const float* __restrict__ bVp,
    float* __restrict__ spart)
{
    const int tid  = threadIdx.x;
    const int lane = tid & 63;
    const int w    = tid >> 6;
    const int b    = blockIdx.z >> 2;
    const int c    = blockIdx.z & 3;           // h-chunk
    const int t0   = blockIdx.y * 16 + w * 4;
    const int s0   = blockIdx.x * 64;
    const int h0   = c * 128;

    float pv = Vp[h0 + lane] + Vp[h0 + 64 + lane];
    #pragma unroll
    for (int off = 32; off; off >>= 1) pv += __shfl_xor(pv, off);
    if (c == 0) pv += bVp[0];

    const float* a0 = abuf + __builtin_amdgcn_readfirstlane((b * T + t0 + 0) * H);
    const float* a1 = abuf + __builtin_amdgcn_readfirstlane((b * T + t0 + 1) * H);
    const float* a2 = abuf + __builtin_amdgcn_readfirstlane((b * T + t0 + 2) * H);
    const float* a3 = abuf + __builtin_amdgcn_readfirstlane((b * T + t0 + 3) * H);

    const float4* bp = (const float4*)bT4 + (size_t)(b * 128 + (h0 >> 2)) * S + s0 + lane;

    float acc0 = 0.f, acc1 = 0.f, acc2 = 0.f, acc3 = 0.f;

    #pragma unroll 4
    for (int h4 = 0; h4 < 32; ++h4) {
        const int h = h0 + h4 * 4;
        float4 kb = bp[(size_t)h4 * S];
        float4 v4  = *(const float4*)&Vp[h];
        float4 qa0 = *(const float4*)&a0[h];
        float4 qa1 = *(const float4*)&a1[h];
        float4 qa2 = *(const float4*)&a2[h];
        float4 qa3 = *(const float4*)&a3[h];
        acc0 = quad_term(qa0, kb, v4, acc0);
        acc1 = quad_term(qa1, kb, v4, acc1);
        acc2 = quad_term(qa2, kb, v4, acc2);
        acc3 = quad_term(qa3, kb, v4, acc3);
    }

    float* out = spart + (size_t)c * BTS;
    const int base = (b * T + t0) * S + s0 + lane;
    out[base + 0 * S] = fmaf(-2.f, acc0, pv);
    out[base + 1 * S] = fmaf(-2.f, acc1, pv);
    out[base + 2 * S] = fmaf(-2.f, acc2, pv);
    out[base + 3 * S] = fmaf(-2.f, acc3, pv);
}

// ---------------------------------------------------------------------------
// K3a: softmax. 8 rows per block (2 per wave). Sums 4 spart chunks.
// ---------------------------------------------------------------------------
__global__ __launch_bounds__(256) void softmax_k(
    const float* __restrict__ spart, float* __restrict__ attnb)
{
    const int lane = threadIdx.x & 63;
    const int w    = threadIdx.x >> 6;

    #pragma unroll
    for (int r = 0; r < 2; ++r) {
        const int row = blockIdx.x * 8 + w * 2 + r;
        const size_t base = (size_t)row * S + lane * 4;

        float4 x0 = make_float4(0.f, 0.f, 0.f, 0.f);
        float4 x1 = make_float4(0.f, 0.f, 0.f, 0.f);
        #pragma unroll
        for (int c = 0; c < 4; ++c) {
            float4 u = *(const float4*)&spart[base + (size_t)c * BTS];
            float4 v = *(const float4*)&spart[base + (size_t)c * BTS + 256];
            x0.x += u.x; x0.y += u.y; x0.z += u.z; x0.w += u.w;
            x1.x += v.x; x1.y += v.y; x1.z += v.z; x1.w += v.w;
        }

        float m = fmaxf(fmaxf(fmaxf(x0.x, x0.y), fmaxf(x0.z, x0.w)),
                        fmaxf(fmaxf(x1.x, x1.y), fmaxf(x1.z, x1.w)));
        #pragma unroll
        for (int off = 32; off; off >>= 1) m = fmaxf(m, __shfl_xor(m, off));

        float4 e0, e1;
        e0.x = EXP2((x0.x - m) * LOG2E); e0.y = EXP2((x0.y - m) * LOG2E);
        e0.z = EXP2((x0.z - m) * LOG2E); e0.w = EXP2((x0.w - m) * LOG2E);
        e1.x = EXP2((x1.x - m) * LOG2E); e1.y = EXP2((x1.y - m) * LOG2E);
        e1.z = EXP2((x1.z - m) * LOG2E); e1.w = EXP2((x1.w - m) * LOG2E);

        float sum = e0.x + e0.y + e0.z + e0.w + e1.x + e1.y + e1.z + e1.w;
        #pragma unroll
        for (int off = 32; off; off >>= 1) sum += __shfl_xor(sum, off);
        const float inv = __builtin_amdgcn_rcpf(sum);

        e0.x *= inv; e0.y *= inv; e0.z *= inv; e0.w *= inv;
        e1.x *= inv; e1.y *= inv; e1.z *= inv; e1.w *= inv;
        *(float4*)&attnb[base]       = e0;
        *(float4*)&attnb[base + 256] = e1;
    }
}

// ---------------------------------------------------------------------------
// K3b: context = attn @ enc.  Block = (b, 16 t, 64 h); attn tile in LDS.
// ---------------------------------------------------------------------------
__global__ __launch_bounds__(256) void ctx_kernel(
    const float* __restrict__ attnb, const float* __restrict__ enc,
    float* __restrict__ out)
{
    __shared__ float at[16][512];

    const int tid = threadIdx.x;
    const int h0  = blockIdx.x * 64;
    const int t0  = blockIdx.y * 16;
    const int b   = blockIdx.z;

    #pragma unroll
    for (int j = 0; j < 8; ++j) {
        const int fidx = j * 256 + tid;
        const int row  = fidx >> 7;
        const int col  = (fidx & 127) * 4;
        float4 v = *(const float4*)&attnb[(size_t)(b * T + t0 + row) * S + col];
        *(float4*)&at[row][col] = v;
    }
    __syncthreads();

    const int tt = tid >> 4;
    const int tc = (tid & 15) * 4;

    float4 acc = make_float4(0.f, 0.f, 0.f, 0.f);
    #pragma unroll 8
    for (int s = 0; s < S; ++s) {
        const float a = at[tt][s];
        float4 e4 = *(const float4*)&enc[(size_t)(b * S + s) * H + h0 + tc];
        acc.x = fmaf(a, e4.x, acc.x);
        acc.y = fmaf(a, e4.y, acc.y);
        acc.z = fmaf(a, e4.z, acc.z);
        acc.w = fmaf(a, e4.w, acc.w);
    }

    *(float4*)&out[(size_t)(b * T + t0 + tt) * H + h0 + tc] = acc;
}

extern "C" void kernel_launch(void* const* d_in, const int* in_sizes, int n_in,
                              void* d_out, int out_size, void* d_ws, size_t ws_size,
                              hipStream_t stream) {
    const float* dh  = (const float*)d_in[0];
    const float* enc = (const float*)d_in[1];
    const float* W1  = (const float*)d_in[2];
    const float* b1  = (const float*)d_in[3];
    const float* W2  = (const float*)d_in[4];
    const float* b2  = (const float*)d_in[5];
    const float* V   = (const float*)d_in[6];
    const float* bV  = (const float*)d_in[7];

    u16* Ahi = (u16*)d_ws;                          // 3072*512 u16 = 3 MB
    u16* Alo = Ahi + 3072 * 512;                    // 3 MB
    u16* Whi = Alo + 3072 * 512;                    // 1024*512 u16 = 1 MB
    u16* Wlo = Whi + 1024 * 512;                    // 1 MB
    float* abuf  = (float*)(Wlo + 1024 * 512);      // B*T*H = 2 MB
    float* bT4   = abuf + (size_t)B * T * H;        // B*S*H = 4 MB
    float* spart = bT4 + (size_t)B * S * H;         // 4*BTS = 8 MB
    float* attnb = spart + 4 * (size_t)BTS;         // 2 MB

    dim3 blk(256);
    convert_split<<<dim3(2048),      blk, 0, stream>>>(dh, enc, W1, W2, Ahi, Alo, Whi, Wlo);
    mfma_proj    <<<dim3(8, 48),     blk, 0, stream>>>(Ahi, Alo, Whi, Wlo, b1, b2, abuf, bT4);
    score_kernel <<<dim3(8, 16, 16), blk, 0, stream>>>(abuf, bT4, V, bV, spart);
    softmax_k    <<<dim3(128),       blk, 0, stream>>>(spart, attnb);
    ctx_kernel   <<<dim3(8, 16, 4),  blk, 0, stream>>>(attnb, enc, (float*)d_out);
}